// Round 1
// baseline (160.020 us; speedup 1.0000x reference)
//
#include <hip/hip_runtime.h>
#include <math.h>

#define E_DIM 8
#define S_DIM 4096
#define B_DIM 8
#define NROWS (B_DIM * S_DIM)          // 32768
#define TSPLIT 8
#define TCHUNK (S_DIM / TSPLIT)        // 512
#define ROWS_PER_BLOCK 256

// 0.5 (attention scale, 1/sqrt(d_k) with d_k=4... actually E/NH=4 -> 0.5) * log2(e)
#define QSCALE 0.72134752044448170f

__device__ inline float fast_exp2(float x) {
#if __has_builtin(__builtin_amdgcn_exp2f)
    return __builtin_amdgcn_exp2f(x);
#else
    return exp2f(x);
#endif
}

// Kernel 1: q/k/v = cos(x @ W.T + b + theta); q additionally scaled by QSCALE.
__global__ __launch_bounds__(256) void qkv_kernel(
    const float* __restrict__ x,
    const float* __restrict__ Wq, const float* __restrict__ bq,
    const float* __restrict__ Wk, const float* __restrict__ bk,
    const float* __restrict__ Wv, const float* __restrict__ bv,
    const float* __restrict__ theta,
    float* __restrict__ Q, float* __restrict__ K, float* __restrict__ V)
{
    int row = blockIdx.x * blockDim.x + threadIdx.x;   // 0..NROWS-1
    const float4* x4 = (const float4*)(x + (size_t)row * E_DIM);
    float4 xa = x4[0], xb = x4[1];
    float xr[8] = {xa.x, xa.y, xa.z, xa.w, xb.x, xb.y, xb.z, xb.w};

    float q[8], k[8], v[8];
#pragma unroll
    for (int i = 0; i < 8; ++i) {
        float hq = bq[i], hk = bk[i], hv = bv[i];
#pragma unroll
        for (int j = 0; j < 8; ++j) {
            hq += xr[j] * Wq[i * 8 + j];
            hk += xr[j] * Wk[i * 8 + j];
            hv += xr[j] * Wv[i * 8 + j];
        }
        float th = theta[i];
        q[i] = cosf(hq + th) * QSCALE;
        k[i] = cosf(hk + th);
        v[i] = cosf(hv + th);
    }

    float4* Q4 = (float4*)(Q + (size_t)row * E_DIM);
    float4* K4 = (float4*)(K + (size_t)row * E_DIM);
    float4* V4 = (float4*)(V + (size_t)row * E_DIM);
    Q4[0] = make_float4(q[0], q[1], q[2], q[3]);
    Q4[1] = make_float4(q[4], q[5], q[6], q[7]);
    K4[0] = make_float4(k[0], k[1], k[2], k[3]);
    K4[1] = make_float4(k[4], k[5], k[6], k[7]);
    V4[0] = make_float4(v[0], v[1], v[2], v[3]);
    V4[1] = make_float4(v[4], v[5], v[6], v[7]);
}

// Kernel 2: flash-style attention partial over a t-chunk.
// No max-subtraction needed: |score*log2e| <= 5.8, exp2 safely bounded.
// grid = (TSPLIT, NROWS/ROWS_PER_BLOCK); block = 256.
__global__ __launch_bounds__(256) void attn_partial_kernel(
    const float* __restrict__ Q, const float* __restrict__ K, const float* __restrict__ V,
    float* __restrict__ ACC, float* __restrict__ DEN)
{
    __shared__ float4 Ks[TCHUNK * 2];   // 16 KB
    __shared__ float4 Vs[TCHUNK * 2];   // 16 KB

    int tc = blockIdx.x;                 // t-chunk index
    int rb = blockIdx.y;                 // row-block index
    int batch = rb >> 4;                 // 16 row-blocks (of 256) per batch of 4096 rows
    int tid = threadIdx.x;

    const float4* Kg = (const float4*)(K + ((size_t)batch * S_DIM + (size_t)tc * TCHUNK) * E_DIM);
    const float4* Vg = (const float4*)(V + ((size_t)batch * S_DIM + (size_t)tc * TCHUNK) * E_DIM);
#pragma unroll
    for (int i = 0; i < (TCHUNK * 2) / 256; ++i) {   // 4 iterations
        Ks[tid + i * 256] = Kg[tid + i * 256];
        Vs[tid + i * 256] = Vg[tid + i * 256];
    }
    __syncthreads();

    int row = rb * ROWS_PER_BLOCK + tid;             // global row, 0..NROWS-1
    const float4* Qg = (const float4*)(Q + (size_t)row * E_DIM);
    float4 q0 = Qg[0], q1 = Qg[1];

    float4 a0 = make_float4(0.f, 0.f, 0.f, 0.f);
    float4 a1 = make_float4(0.f, 0.f, 0.f, 0.f);
    float den = 0.f;

#pragma unroll 4
    for (int t = 0; t < TCHUNK; ++t) {
        // uniform address across the wave -> LDS broadcast, conflict-free
        float4 k0 = Ks[2 * t], k1 = Ks[2 * t + 1];
        float d = q0.x * k0.x + q0.y * k0.y + q0.z * k0.z + q0.w * k0.w
                + q1.x * k1.x + q1.y * k1.y + q1.z * k1.z + q1.w * k1.w;
        float w = fast_exp2(d);
        float4 v0 = Vs[2 * t], v1 = Vs[2 * t + 1];
        den += w;
        a0.x += w * v0.x; a0.y += w * v0.y; a0.z += w * v0.z; a0.w += w * v0.w;
        a1.x += w * v1.x; a1.y += w * v1.y; a1.z += w * v1.z; a1.w += w * v1.w;
    }

    float4* ACC4 = (float4*)(ACC + ((size_t)tc * NROWS + row) * E_DIM);
    ACC4[0] = a0;
    ACC4[1] = a1;
    DEN[(size_t)tc * NROWS + row] = den;
}

// Kernel 3: reduce partials across t-chunks, normalize, apply output projection.
__global__ __launch_bounds__(256) void finalize_kernel(
    const float* __restrict__ ACC, const float* __restrict__ DEN,
    const float* __restrict__ Wc, const float* __restrict__ bc,
    float* __restrict__ out)
{
    int row = blockIdx.x * blockDim.x + threadIdx.x;
    float4 a0 = make_float4(0.f, 0.f, 0.f, 0.f);
    float4 a1 = make_float4(0.f, 0.f, 0.f, 0.f);
    float den = 0.f;
#pragma unroll
    for (int tc = 0; tc < TSPLIT; ++tc) {
        const float4* A4 = (const float4*)(ACC + ((size_t)tc * NROWS + row) * E_DIM);
        float4 p0 = A4[0], p1 = A4[1];
        a0.x += p0.x; a0.y += p0.y; a0.z += p0.z; a0.w += p0.w;
        a1.x += p1.x; a1.y += p1.y; a1.z += p1.z; a1.w += p1.w;
        den += DEN[(size_t)tc * NROWS + row];
    }
    float inv = 1.0f / den;
    float o[8] = {a0.x * inv, a0.y * inv, a0.z * inv, a0.w * inv,
                  a1.x * inv, a1.y * inv, a1.z * inv, a1.w * inv};
    float r[8];
#pragma unroll
    for (int i = 0; i < 8; ++i) {
        float h = bc[i];
#pragma unroll
        for (int j = 0; j < 8; ++j) h += o[j] * Wc[i * 8 + j];
        r[i] = h;
    }
    float4* O4 = (float4*)(out + (size_t)row * E_DIM);
    O4[0] = make_float4(r[0], r[1], r[2], r[3]);
    O4[1] = make_float4(r[4], r[5], r[6], r[7]);
}

extern "C" void kernel_launch(void* const* d_in, const int* in_sizes, int n_in,
                              void* d_out, int out_size, void* d_ws, size_t ws_size,
                              hipStream_t stream) {
    const float* x     = (const float*)d_in[0];
    const float* Wq    = (const float*)d_in[1];
    const float* bq    = (const float*)d_in[2];
    const float* Wk    = (const float*)d_in[3];
    const float* bk    = (const float*)d_in[4];
    const float* Wv    = (const float*)d_in[5];
    const float* bv    = (const float*)d_in[6];
    const float* theta = (const float*)d_in[7];
    const float* Wc    = (const float*)d_in[8];
    const float* bc    = (const float*)d_in[9];
    float* out = (float*)d_out;

    // Workspace carve-up (floats):
    // Q: NROWS*8, K: NROWS*8, V: NROWS*8, ACC: TSPLIT*NROWS*8, DEN: TSPLIT*NROWS
    float* ws = (float*)d_ws;
    float* Q   = ws;
    float* K   = Q + (size_t)NROWS * E_DIM;
    float* V   = K + (size_t)NROWS * E_DIM;
    float* ACC = V + (size_t)NROWS * E_DIM;
    float* DEN = ACC + (size_t)TSPLIT * NROWS * E_DIM;
    // total = 3*262144 + 2097152 + 262144 = 3,145,728 floats = 12.6 MB

    qkv_kernel<<<NROWS / 256, 256, 0, stream>>>(x, Wq, bq, Wk, bk, Wv, bv, theta, Q, K, V);

    dim3 grid2(TSPLIT, NROWS / ROWS_PER_BLOCK);   // (8, 128)
    attn_partial_kernel<<<grid2, 256, 0, stream>>>(Q, K, V, ACC, DEN);

    finalize_kernel<<<NROWS / 256, 256, 0, stream>>>(ACC, DEN, Wc, bc, out);
}